// Round 6
// baseline (139.925 us; speedup 1.0000x reference)
//
#include <hip/hip_runtime.h>

#define NB 16
#define NA 76725
#define NC 8
#define NM 32
#define FEPS 1e-4f
#define APT 2                     // anchors per thread
#define TPB 128                   // 2 waves/block
#define ANCH_PER_BLK (APT * TPB)  // 256
#define NBLK_X ((NA + ANCH_PER_BLK - 1) / ANCH_PER_BLK)   // 300
#define NBLK_TOT (NBLK_X * NB)                            // 4800

// ws layout (floats):
//  [WS_ACC  .. +NB*16)   per-image acc: {cls_sum, reg_sum, npos(uint), pad..} 64B stride
//  [WS_NVP  .. +16)      padded valid count per image
//  [WS_CNT  .. +16)      num_valid per image
//  [WS_DONE .. +16)      done-counter (uint) + pad
//  [WS_REC  .. +NB*NM*8) per (b,m) record {x1,y1,x2+1,y2+1,area2,lab,pad,pad} (32B)
//  [WS_EPI  .. +NB*NM*4) per (b,m) float4 {gcx,gcy,log(gw),log(gh)}
#define WS_ACC  0
#define WS_NVP  (NB * 16)           // 256
#define WS_CNT  (WS_NVP + 16)       // 272
#define WS_DONE (WS_CNT + 16)       // 288 (uint at this float index)
#define WS_REC  (WS_DONE + 16)      // 304 (16B aligned)
#define WS_EPI  (WS_REC + NB * NM * 8)

__global__ __launch_bounds__(64) void focal_prep(
    const float* __restrict__ ann_, float* __restrict__ ws)
{
    const int b = blockIdx.x;
    const int m = threadIdx.x;
    if (m < 16) ws[WS_ACC + b * 16 + m] = 0.f;       // zero this image's acc line
    if (m == 17) reinterpret_cast<unsigned*>(ws)[WS_DONE] = 0u;  // same value from 16 blocks: benign
    bool valid = false;
    float x1 = 0.f, y1 = 0.f, x2 = 0.f, y2 = 0.f, lab = -1.f;
    if (m < NM) {
        const float* r = ann_ + ((size_t)b * NM + m) * 5;
        x1 = r[0]; y1 = r[1]; x2 = r[2]; y2 = r[3]; lab = r[4];
        valid = lab > -0.5f;
        // sentinel record: inter==0 -> never beats init (ib=0, ub=1)
        float* rec = ws + WS_REC + ((size_t)b * NM + m) * 8;
        rec[0] = 3e18f; rec[1] = 3e18f; rec[2] = -3e18f; rec[3] = -3e18f;
        rec[4] = 1.0f;  rec[5] = -1.f;  rec[6] = 0.f;    rec[7] = 0.f;
        reinterpret_cast<float4*>(ws + WS_EPI)[b * NM + m] = make_float4(0.f, 0.f, 0.f, 0.f);
    }
    const unsigned long long mask = __ballot(valid);
    const int cnt = __popcll(mask);
    __syncthreads();
    if (valid) {
        const int idx = __popcll(mask & ((1ull << m) - 1ull));  // stable compaction
        float* rec = ws + WS_REC + ((size_t)b * NM + idx) * 8;
        rec[0] = x1; rec[1] = y1; rec[2] = x2 + 1.f; rec[3] = y2 + 1.f;
        rec[4] = (x2 - x1 + 1.f) * (y2 - y1 + 1.f);
        rec[5] = lab;
        const float w0 = x2 - x1, h0 = y2 - y1;
        reinterpret_cast<float4*>(ws + WS_EPI)[b * NM + idx] =
            make_float4(x1 + 0.5f * w0, y1 + 0.5f * h0,
                        __logf(fmaxf(w0, 1.f)), __logf(fmaxf(h0, 1.f)));
    }
    if (m == 0) {
        ws[WS_CNT + b] = (float)cnt;
        ws[WS_NVP + b] = (float)((cnt + 7) & ~7);
    }
}

__global__ __launch_bounds__(TPB, 4) void focal_main(
    const float* __restrict__ cls_,
    const float* __restrict__ reg_,
    const float* __restrict__ anch_,
    const float* __restrict__ tab,
    float* __restrict__ acc,
    float* __restrict__ out)
{
    const int b   = blockIdx.y;
    const int tid = threadIdx.x;

    __shared__ float4 s_box[NM];          // {x1,y1,x2+1,y2+1} -> 1 ds_read_b128/iter
    __shared__ float  s_a2[NM], s_lab[NM];
    __shared__ float4 s_epi[NM];
    if (tid < NM) {
        const float4 r0 = reinterpret_cast<const float4*>(tab + WS_REC)[(b * NM + tid) * 2];
        const float4 r1 = reinterpret_cast<const float4*>(tab + WS_REC)[(b * NM + tid) * 2 + 1];
        s_box[tid] = r0;
        s_a2[tid] = r1.x; s_lab[tid] = r1.y;
        s_epi[tid] = reinterpret_cast<const float4*>(tab + WS_EPI)[b * NM + tid];
    }
    int nvp = (int)tab[WS_NVP + b];
    nvp = __builtin_amdgcn_readfirstlane(nvp);   // wave-uniform scalar loop bound
    __syncthreads();

    const int a0 = blockIdx.x * ANCH_PER_BLK + tid;

    // ---- issue ALL global loads up front (8x dwordx4 in flight per thread)
    bool   amask[APT];
    float4 an[APT], rg[APT], cv0[APT], cv1[APT];
    #pragma unroll
    for (int k = 0; k < APT; ++k) {
        const int a = a0 + k * TPB;
        amask[k] = (a < NA);
        const int ac = amask[k] ? a : (NA - 1);        // clamp, mask later
        const size_t base = (size_t)b * NA + ac;
        an[k]  = reinterpret_cast<const float4*>(anch_)[base];
        rg[k]  = reinterpret_cast<const float4*>(reg_)[base];
        cv0[k] = reinterpret_cast<const float4*>(cls_)[base * 2];
        cv1[k] = reinterpret_cast<const float4*>(cls_)[base * 2 + 1];
    }

    float ax[APT], ay[APT], az1[APT], aw1[APT], area1[APT];
    float ib[APT], ub[APT];
    int   arg[APT];
    #pragma unroll
    for (int k = 0; k < APT; ++k) {
        ax[k]  = an[k].x; ay[k] = an[k].y;
        az1[k] = an[k].z + 1.f; aw1[k] = an[k].w + 1.f;
        area1[k] = (an[k].z - ax[k] + 1.f) * (an[k].w - ay[k] + 1.f);
        ib[k] = 0.f; ub[k] = 1.f; arg[k] = 0;
    }

    #pragma unroll 4
    for (int m = 0; m < nvp; ++m) {
        const float4 q = s_box[m];                 // broadcast ds_read_b128
        const float a2 = s_a2[m];                  // broadcast ds_read_b32
        #pragma unroll
        for (int k = 0; k < APT; ++k) {
            const float w = fminf(az1[k], q.z) - fmaxf(ax[k], q.x);
            const float h = fminf(aw1[k], q.w) - fmaxf(ay[k], q.y);
            const float inter = fmaxf(w, 0.f) * fmaxf(h, 0.f);
            const float u = area1[k] + a2 - inter;
            const bool better = inter * ub[k] > ib[k] * u;  // strict >: first-occurrence
            ib[k]  = better ? inter : ib[k];
            ub[k]  = better ? u : ub[k];
            arg[k] = better ? m : arg[k];
        }
    }

    float cls_c = 0.f, reg_c = 0.f;
    unsigned pos_c = 0;

    #pragma unroll
    for (int k = 0; k < APT; ++k) {
        const bool pos = ib[k] >= 0.4f * ub[k];
        const bool neg = ib[k] <  0.3f * ub[k];
        const bool act = (pos || neg) && amask[k];

        float pcl[8];
        {
            const float pv[8] = {cv0[k].x, cv0[k].y, cv0[k].z, cv0[k].w,
                                 cv1[k].x, cv1[k].y, cv1[k].z, cv1[k].w};
            float bsum = 0.f;
            #pragma unroll
            for (int c = 0; c < NC; ++c) {
                const float p = fminf(fmaxf(pv[c], FEPS), 1.f - FEPS);
                pcl[c] = p;
                bsum += 0.75f * p * p * (-__logf(1.f - p));   // 8 independent chains
            }
            float contrib = bsum;
            if (pos) {
                const int labi = (int)s_lab[arg[k]];
                const float t0 = (labi & 1) ? pcl[1] : pcl[0];
                const float t1 = (labi & 1) ? pcl[3] : pcl[2];
                const float t2 = (labi & 1) ? pcl[5] : pcl[4];
                const float t3 = (labi & 1) ? pcl[7] : pcl[6];
                const float u0 = (labi & 2) ? t1 : t0;
                const float u1 = (labi & 2) ? t3 : t2;
                const float pt = (labi & 4) ? u1 : u0;
                const float om = 1.f - pt;
                contrib += 0.25f * om * om * (-__logf(pt))
                         - 0.75f * pt * pt * (-__logf(om));
            }
            cls_c += act ? contrib : 0.f;
        }

        if (pos && amask[k]) {
            pos_c += 1;
            const float4 ep = s_epi[arg[k]];
            const float awd = az1[k] - 1.f - ax[k];    // no +1 for regression geometry
            const float ahd = aw1[k] - 1.f - ay[k];
            const float acx = ax[k] + 0.5f * awd;
            const float acy = ay[k] + 0.5f * ahd;
            const float t0 = __fdividef(ep.x - acx, awd) * 10.f;
            const float t1 = __fdividef(ep.y - acy, ahd) * 10.f;
            const float t2 = (ep.z - __logf(awd)) * 5.f;
            const float t3 = (ep.w - __logf(ahd)) * 5.f;
            const float d0 = fabsf(t0 - rg[k].x);
            const float d1 = fabsf(t1 - rg[k].y);
            const float d2 = fabsf(t2 - rg[k].z);
            const float d3 = fabsf(t3 - rg[k].w);
            auto sl1 = [](float d) {
                return d <= (1.f / 9.f) ? 4.5f * d * d : d - (0.5f / 9.f);
            };
            reg_c += sl1(d0) + sl1(d1) + sl1(d2) + sl1(d3);
        }
    }

    // wave reduction, cross-wave via LDS, one atomic triplet per block
    #pragma unroll
    for (int off = 32; off > 0; off >>= 1) {
        cls_c += __shfl_down(cls_c, off);
        reg_c += __shfl_down(reg_c, off);
        pos_c += __shfl_down(pos_c, off);
    }
    __shared__ float    sc[2], sr[2];
    __shared__ unsigned sp[2];
    const int wave = tid >> 6, lane = tid & 63;
    if (lane == 0) { sc[wave] = cls_c; sr[wave] = reg_c; sp[wave] = pos_c; }
    __syncthreads();

    unsigned* const done = reinterpret_cast<unsigned*>(acc) + WS_DONE;
    bool last = false;
    if (tid == 0) {
        atomicAdd(&acc[WS_ACC + b * 16 + 0], sc[0] + sc[1]);
        atomicAdd(&acc[WS_ACC + b * 16 + 1], sr[0] + sr[1]);
        atomicAdd(reinterpret_cast<unsigned*>(acc) + WS_ACC + b * 16 + 2, sp[0] + sp[1]);
        __threadfence();                                  // release our adds
        last = (atomicAdd(done, 1u) == NBLK_TOT - 1u);
    }
    // inline finalize: the globally-last block computes the output (wave 0 only)
    if (tid < 64) {
        last = (bool)__shfl((int)last, 0);
        if (last) {
            __threadfence();                              // acquire all adds
            float cl = 0.f, rl = 0.f;
            if (tid < NB) {
                const int i = tid;
                const float nv = tab[WS_CNT + i];
                // coherent re-reads via device-scope RMW (+0)
                const float    cs = atomicAdd(&acc[WS_ACC + i * 16 + 0], 0.f);
                const float    rs = atomicAdd(&acc[WS_ACC + i * 16 + 1], 0.f);
                const unsigned np = atomicAdd(reinterpret_cast<unsigned*>(acc) + WS_ACC + i * 16 + 2, 0u);
                cl = cs / fmaxf((float)np, 1.f);
                rl = (np > 0u) ? rs / (float)(np * 4u) : 0.f;
                if (nv < 0.5f) { cl = 0.f; rl = 0.f; }
            }
            #pragma unroll
            for (int off = 8; off > 0; off >>= 1) {
                cl += __shfl_down(cl, off);
                rl += __shfl_down(rl, off);
            }
            if (tid == 0) {
                out[0] = cl * (1.f / NB);
                out[1] = rl * (1.f / NB);
            }
        }
    }
}

extern "C" void kernel_launch(void* const* d_in, const int* in_sizes, int n_in,
                              void* d_out, int out_size, void* d_ws, size_t ws_size,
                              hipStream_t stream)
{
    const float* cls_  = (const float*)d_in[0];
    const float* reg_  = (const float*)d_in[1];
    const float* anch_ = (const float*)d_in[2];
    const float* ann_  = (const float*)d_in[3];
    float* ws  = (float*)d_ws;
    float* out = (float*)d_out;

    focal_prep<<<NB, 64, 0, stream>>>(ann_, ws);
    dim3 grid(NBLK_X, NB);
    focal_main<<<grid, dim3(TPB), 0, stream>>>(cls_, reg_, anch_, ws, ws, out);
}

// Round 7
// 45.416 us; speedup vs baseline: 3.0810x; 3.0810x over previous
//
#include <hip/hip_runtime.h>

#define NB 16
#define NA 76725
#define NC 8
#define NM 32
#define FEPS 1e-4f
#define APT 2                     // anchors per thread
#define TPB 256
#define ANCH_PER_BLK (APT * TPB)  // 512
#define NBLK_X ((NA + ANCH_PER_BLK - 1) / ANCH_PER_BLK)   // 150

// ws layout (floats):
//  [WS_ACC .. +NB*16)   per-image acc: {cls_sum, reg_sum, npos(uint), pad..} 64B stride
//  [WS_NVP .. +16)      padded valid count per image
//  [WS_CNT .. +16)      num_valid per image
//  [WS_REC .. +NB*NM*8) per (b,m) record {x1,y1,x2+1,y2+1,area2,lab,pad,pad} (32B)
//  [WS_EPI .. +NB*NM*4) per (b,m) float4 {gcx,gcy,log(gw),log(gh)}
#define WS_ACC 0
#define WS_NVP (NB * 16)            // 256
#define WS_CNT (WS_NVP + 16)        // 272
#define WS_REC (WS_CNT + 16)        // 288 (16B aligned)
#define WS_EPI (WS_REC + NB * NM * 8)

__global__ __launch_bounds__(64) void focal_prep(
    const float* __restrict__ ann_, float* __restrict__ ws)
{
    const int b = blockIdx.x;
    const int m = threadIdx.x;
    if (m < 16) ws[WS_ACC + b * 16 + m] = 0.f;   // zero this image's acc line
    bool valid = false;
    float x1 = 0.f, y1 = 0.f, x2 = 0.f, y2 = 0.f, lab = -1.f;
    if (m < NM) {
        const float* r = ann_ + ((size_t)b * NM + m) * 5;
        x1 = r[0]; y1 = r[1]; x2 = r[2]; y2 = r[3]; lab = r[4];
        valid = lab > -0.5f;
        // sentinel record: inter==0 -> never beats init (ib=0, ub=1)
        float* rec = ws + WS_REC + ((size_t)b * NM + m) * 8;
        rec[0] = 3e18f; rec[1] = 3e18f; rec[2] = -3e18f; rec[3] = -3e18f;
        rec[4] = 1.0f;  rec[5] = -1.f;  rec[6] = 0.f;    rec[7] = 0.f;
        reinterpret_cast<float4*>(ws + WS_EPI)[b * NM + m] = make_float4(0.f, 0.f, 0.f, 0.f);
    }
    const unsigned long long mask = __ballot(valid);
    const int cnt = __popcll(mask);
    __syncthreads();
    if (valid) {
        const int idx = __popcll(mask & ((1ull << m) - 1ull));  // stable compaction
        float* rec = ws + WS_REC + ((size_t)b * NM + idx) * 8;
        rec[0] = x1; rec[1] = y1; rec[2] = x2 + 1.f; rec[3] = y2 + 1.f;
        rec[4] = (x2 - x1 + 1.f) * (y2 - y1 + 1.f);
        rec[5] = lab;
        const float w0 = x2 - x1, h0 = y2 - y1;
        reinterpret_cast<float4*>(ws + WS_EPI)[b * NM + idx] =
            make_float4(x1 + 0.5f * w0, y1 + 0.5f * h0,
                        __logf(fmaxf(w0, 1.f)), __logf(fmaxf(h0, 1.f)));
    }
    if (m == 0) {
        ws[WS_CNT + b] = (float)cnt;
        ws[WS_NVP + b] = (float)((cnt + 7) & ~7);
    }
}

// R3 structure: LDS broadcast tables + batched upfront loads; APT=2 for TLP;
// sched_barrier pins the load cluster so the scheduler can't serialize it.
__global__ __launch_bounds__(TPB, 4) void focal_main(
    const float* __restrict__ cls_,
    const float* __restrict__ reg_,
    const float* __restrict__ anch_,
    const float* __restrict__ tab,
    float* __restrict__ acc)
{
    const int b   = blockIdx.y;
    const int tid = threadIdx.x;

    __shared__ float  s_x1[NM], s_y1[NM], s_x21[NM], s_y21[NM], s_a2[NM], s_lab[NM];
    __shared__ float4 s_epi[NM];
    if (tid < NM) {
        const float4 r0 = reinterpret_cast<const float4*>(tab + WS_REC)[(b * NM + tid) * 2];
        const float4 r1 = reinterpret_cast<const float4*>(tab + WS_REC)[(b * NM + tid) * 2 + 1];
        s_x1[tid] = r0.x; s_y1[tid] = r0.y; s_x21[tid] = r0.z; s_y21[tid] = r0.w;
        s_a2[tid] = r1.x; s_lab[tid] = r1.y;
        s_epi[tid] = reinterpret_cast<const float4*>(tab + WS_EPI)[b * NM + tid];
    }
    int nvp = (int)tab[WS_NVP + b];
    nvp = __builtin_amdgcn_readfirstlane(nvp);   // wave-uniform scalar loop bound
    __syncthreads();

    const int a0 = blockIdx.x * ANCH_PER_BLK + tid;

    // ---- issue ALL global loads up front (8x dwordx4 in flight per thread)
    bool   amask[APT];
    float4 an[APT], rg[APT], cv0[APT], cv1[APT];
    #pragma unroll
    for (int k = 0; k < APT; ++k) {
        const int a = a0 + k * TPB;
        amask[k] = (a < NA);
        const int ac = amask[k] ? a : (NA - 1);        // clamp, mask later
        const size_t base = (size_t)b * NA + ac;
        an[k]  = reinterpret_cast<const float4*>(anch_)[base];
        rg[k]  = reinterpret_cast<const float4*>(reg_)[base];
        cv0[k] = reinterpret_cast<const float4*>(cls_)[base * 2];
        cv1[k] = reinterpret_cast<const float4*>(cls_)[base * 2 + 1];
    }
    // Pin the cluster: nothing moves across (loads can't sink past their
    // consumers' region; the m-loop can't hoist above). All 8 stay in flight.
    __builtin_amdgcn_sched_barrier(0);

    float ax[APT], ay[APT], az1[APT], aw1[APT], area1[APT];
    float ib[APT], ub[APT];
    int   arg[APT];
    #pragma unroll
    for (int k = 0; k < APT; ++k) {
        ax[k]  = an[k].x; ay[k] = an[k].y;
        az1[k] = an[k].z + 1.f; aw1[k] = an[k].w + 1.f;
        area1[k] = (an[k].z - ax[k] + 1.f) * (an[k].w - ay[k] + 1.f);
        ib[k] = 0.f; ub[k] = 1.f; arg[k] = 0;
    }

    #pragma unroll 4
    for (int m = 0; m < nvp; ++m) {
        const float x1 = s_x1[m], y1 = s_y1[m];        // LDS broadcast reads
        const float x21 = s_x21[m], y21 = s_y21[m];
        const float a2 = s_a2[m];
        #pragma unroll
        for (int k = 0; k < APT; ++k) {
            const float w = fminf(az1[k], x21) - fmaxf(ax[k], x1);
            const float h = fminf(aw1[k], y21) - fmaxf(ay[k], y1);
            const float inter = fmaxf(w, 0.f) * fmaxf(h, 0.f);
            const float u = area1[k] + a2 - inter;
            const bool better = inter * ub[k] > ib[k] * u;  // strict >: first-occurrence
            ib[k]  = better ? inter : ib[k];
            ub[k]  = better ? u : ub[k];
            arg[k] = better ? m : arg[k];
        }
    }

    float cls_c = 0.f, reg_c = 0.f;
    unsigned pos_c = 0;

    #pragma unroll
    for (int k = 0; k < APT; ++k) {
        const bool pos = ib[k] >= 0.4f * ub[k];
        const bool neg = ib[k] <  0.3f * ub[k];
        const bool act = (pos || neg) && amask[k];

        float pcl[8];
        {
            const float pv[8] = {cv0[k].x, cv0[k].y, cv0[k].z, cv0[k].w,
                                 cv1[k].x, cv1[k].y, cv1[k].z, cv1[k].w};
            float bsum = 0.f;
            #pragma unroll
            for (int c = 0; c < NC; ++c) {
                const float p = fminf(fmaxf(pv[c], FEPS), 1.f - FEPS);
                pcl[c] = p;
                bsum += 0.75f * p * p * (-__logf(1.f - p));   // 8 independent chains
            }
            float contrib = bsum;
            if (pos) {
                const int labi = (int)s_lab[arg[k]];
                const float t0 = (labi & 1) ? pcl[1] : pcl[0];
                const float t1 = (labi & 1) ? pcl[3] : pcl[2];
                const float t2 = (labi & 1) ? pcl[5] : pcl[4];
                const float t3 = (labi & 1) ? pcl[7] : pcl[6];
                const float u0 = (labi & 2) ? t1 : t0;
                const float u1 = (labi & 2) ? t3 : t2;
                const float pt = (labi & 4) ? u1 : u0;
                const float om = 1.f - pt;
                contrib += 0.25f * om * om * (-__logf(pt))
                         - 0.75f * pt * pt * (-__logf(om));
            }
            cls_c += act ? contrib : 0.f;
        }

        if (pos && amask[k]) {
            pos_c += 1;
            const float4 ep = s_epi[arg[k]];
            const float awd = az1[k] - 1.f - ax[k];    // no +1 for regression geometry
            const float ahd = aw1[k] - 1.f - ay[k];
            const float acx = ax[k] + 0.5f * awd;
            const float acy = ay[k] + 0.5f * ahd;
            const float t0 = __fdividef(ep.x - acx, awd) * 10.f;
            const float t1 = __fdividef(ep.y - acy, ahd) * 10.f;
            const float t2 = (ep.z - __logf(awd)) * 5.f;
            const float t3 = (ep.w - __logf(ahd)) * 5.f;
            const float d0 = fabsf(t0 - rg[k].x);
            const float d1 = fabsf(t1 - rg[k].y);
            const float d2 = fabsf(t2 - rg[k].z);
            const float d3 = fabsf(t3 - rg[k].w);
            auto sl1 = [](float d) {
                return d <= (1.f / 9.f) ? 4.5f * d * d : d - (0.5f / 9.f);
            };
            reg_c += sl1(d0) + sl1(d1) + sl1(d2) + sl1(d3);
        }
    }

    // wave-64 shuffle reduction, cross-wave via LDS, 3 atomics per block
    #pragma unroll
    for (int off = 32; off > 0; off >>= 1) {
        cls_c += __shfl_down(cls_c, off);
        reg_c += __shfl_down(reg_c, off);
        pos_c += __shfl_down(pos_c, off);
    }
    __shared__ float    sc[4], sr[4];
    __shared__ unsigned sp[4];
    const int wave = tid >> 6, lane = tid & 63;
    if (lane == 0) { sc[wave] = cls_c; sr[wave] = reg_c; sp[wave] = pos_c; }
    __syncthreads();
    if (tid == 0) {
        const float    c = sc[0] + sc[1] + sc[2] + sc[3];
        const float    r = sr[0] + sr[1] + sr[2] + sr[3];
        const unsigned p = sp[0] + sp[1] + sp[2] + sp[3];
        atomicAdd(&acc[WS_ACC + b * 16 + 0], c);
        atomicAdd(&acc[WS_ACC + b * 16 + 1], r);
        atomicAdd(reinterpret_cast<unsigned*>(acc) + WS_ACC + b * 16 + 2, p);
    }
}

__global__ __launch_bounds__(64) void focal_finalize(
    const float* __restrict__ ws, float* __restrict__ out)
{
    __shared__ float s_cls[NB], s_reg[NB];
    const int b = threadIdx.x;
    if (b < NB) {
        const float    nv      = ws[WS_CNT + b];
        const float    cls_sum = ws[WS_ACC + b * 16 + 0];
        const float    reg_sum = ws[WS_ACC + b * 16 + 1];
        const unsigned npos    = reinterpret_cast<const unsigned*>(ws)[WS_ACC + b * 16 + 2];
        float cl = cls_sum / fmaxf((float)npos, 1.f);
        float rl = (npos > 0u) ? reg_sum / (float)(npos * 4u) : 0.f;
        if (nv < 0.5f) { cl = 0.f; rl = 0.f; }
        s_cls[b] = cl;
        s_reg[b] = rl;
    }
    __syncthreads();
    if (threadIdx.x == 0) {
        float c = 0.f, r = 0.f;
        for (int i = 0; i < NB; ++i) { c += s_cls[i]; r += s_reg[i]; }
        out[0] = c * (1.f / NB);
        out[1] = r * (1.f / NB);
    }
}

extern "C" void kernel_launch(void* const* d_in, const int* in_sizes, int n_in,
                              void* d_out, int out_size, void* d_ws, size_t ws_size,
                              hipStream_t stream)
{
    const float* cls_  = (const float*)d_in[0];
    const float* reg_  = (const float*)d_in[1];
    const float* anch_ = (const float*)d_in[2];
    const float* ann_  = (const float*)d_in[3];
    float* ws  = (float*)d_ws;
    float* out = (float*)d_out;

    focal_prep<<<NB, 64, 0, stream>>>(ann_, ws);
    dim3 grid(NBLK_X, NB);
    focal_main<<<grid, dim3(TPB), 0, stream>>>(cls_, reg_, anch_, ws, ws);
    focal_finalize<<<1, 64, 0, stream>>>(ws, out);
}